// Round 1
// baseline (319.210 us; speedup 1.0000x reference)
//
#include <hip/hip_runtime.h>

// Problem constants (from reference)
constexpr int B_ = 4, T_ = 12, N_ = 2000, K_ = 10, F_ = 64, H_ = 8;
constexpr float INV_SIG2 = 1.0f / 36.0f;   // 1/sigma^2, sigma=6

// LDS strides (chosen for conflict-freedom + 16B alignment, see analysis)
constexpr int WS_STRIDE = 65;   // WsT[f*65 + fo] = W[fo*64 + f]
constexpr int BL_STRIDE = 100;  // blL[f*100 + t*8 + h]; 400B rows -> float4-aligned

__global__ __launch_bounds__(256, 2)
void gconv_fused(const float* __restrict__ x,
                 const float* __restrict__ dist,
                 const float* __restrict__ W,
                 const float* __restrict__ bias,
                 const int*   __restrict__ idx,
                 float* __restrict__ out)
{
    __shared__ float WsT[F_ * WS_STRIDE];   // 16.6 KB, W transposed
    __shared__ float blL[F_ * BL_STRIDE];   // 25.6 KB, blended agg, [f][t*8+h]

    const int tid  = threadIdx.x;      // 0..255
    const int wave = tid >> 6;         // 0..3
    const int lane = tid & 63;         // 0..63
    const int bid  = blockIdx.x;       // 0..B*N-1
    const int n = bid % N_;
    const int b = bid / N_;

    // ---- Stage W transposed into LDS (write stride 65 -> conflict-free) ----
    #pragma unroll
    for (int j = 0; j < (F_ * F_) / 256; ++j) {
        int i = j * 256 + tid;                 // i = fo*64 + f (row-major W)
        WsT[(i & 63) * WS_STRIDE + (i >> 6)] = W[i];
    }

    // ---- Neighbor indices (block-uniform -> scalar loads) + head weights ----
    const int h0 = wave * 2;                   // this wave's head pair
    int   nb[K_];
    float wk0[K_], wk1[K_];
    #pragma unroll
    for (int k = 0; k < K_; ++k) {
        nb[k] = idx[n * K_ + k] * F_;
        float d = dist[n * K_ + k];
        float e = -d * d * INV_SIG2 * (1.0f / (float)H_);  // -d^2/36 * (1/8)
        wk0[k] = __expf(e * (float)(h0 + 1));  // lam = (h+1)/8
        wk1[k] = __expf(e * (float)(h0 + 2));
    }

    // ---- Phase 1: agg[t][h0], agg[t][h0+1] for f = lane, all t ----
    float ag0[T_], ag1[T_];
    #pragma unroll
    for (int t = 0; t < T_; ++t) { ag0[t] = 0.f; ag1[t] = 0.f; }

    const float* xb = x + (size_t)b * T_ * N_ * F_ + lane;
    #pragma unroll
    for (int t = 0; t < T_; ++t) {
        const float* xt = xb + (size_t)t * N_ * F_;
        #pragma unroll
        for (int k = 0; k < K_; ++k) {
            float xv = xt[nb[k]];              // coalesced 256B row per (t,k)
            ag0[t] = fmaf(xv, wk0[k], ag0[t]);
            ag1[t] = fmaf(xv, wk1[k], ag1[t]);
        }
    }

    // ---- Temporal blend, in registers, descending t (t=0 stays raw) ----
    #pragma unroll
    for (int t = T_ - 1; t >= 1; --t) {
        ag0[t] = 0.8f * ag0[t] + 0.2f * ag0[t - 1];
        ag1[t] = 0.8f * ag1[t] + 0.2f * ag1[t - 1];
    }

    // ---- Write blended to LDS: blL[f=lane][t*8 + h0..h0+1] (float2) ----
    #pragma unroll
    for (int t = 0; t < T_; ++t) {
        *(float2*)&blL[lane * BL_STRIDE + t * 8 + h0] = make_float2(ag0[t], ag1[t]);
    }
    __syncthreads();

    // ---- Phase 2: GEMM. wave owns t in [3w, 3w+3), all h, fo = lane ----
    const int t0 = wave * 3;
    float acc[3][H_];
    #pragma unroll
    for (int i = 0; i < 3; ++i)
        #pragma unroll
        for (int h = 0; h < H_; ++h) acc[i][h] = 0.f;

    #pragma unroll 4
    for (int f = 0; f < F_; ++f) {
        float wv = WsT[f * WS_STRIDE + lane];          // conflict-free column read
        const float* blp = &blL[f * BL_STRIDE + t0 * 8];
        #pragma unroll
        for (int i = 0; i < 3; ++i) {
            float4 lo = *(const float4*)(blp + i * 8);       // broadcast reads
            float4 hi = *(const float4*)(blp + i * 8 + 4);
            acc[i][0] = fmaf(lo.x, wv, acc[i][0]);
            acc[i][1] = fmaf(lo.y, wv, acc[i][1]);
            acc[i][2] = fmaf(lo.z, wv, acc[i][2]);
            acc[i][3] = fmaf(lo.w, wv, acc[i][3]);
            acc[i][4] = fmaf(hi.x, wv, acc[i][4]);
            acc[i][5] = fmaf(hi.y, wv, acc[i][5]);
            acc[i][6] = fmaf(hi.z, wv, acc[i][6]);
            acc[i][7] = fmaf(hi.w, wv, acc[i][7]);
        }
    }

    // ---- Bias + ReLU + coalesced store ----
    const float bs = bias[lane];
    #pragma unroll
    for (int i = 0; i < 3; ++i) {
        #pragma unroll
        for (int h = 0; h < H_; ++h) {
            float v = fmaxf(acc[i][h] + bs, 0.f);
            out[(size_t)(((b * T_ + t0 + i) * N_ + n) * H_ + h) * F_ + lane] = v;
        }
    }
}

extern "C" void kernel_launch(void* const* d_in, const int* in_sizes, int n_in,
                              void* d_out, int out_size, void* d_ws, size_t ws_size,
                              hipStream_t stream) {
    const float* x    = (const float*)d_in[0];
    const float* dist = (const float*)d_in[1];
    const float* W    = (const float*)d_in[2];
    const float* bias = (const float*)d_in[3];
    const int*   idx  = (const int*)d_in[4];
    float* out = (float*)d_out;

    dim3 grid(B_ * N_);
    dim3 block(256);
    hipLaunchKernelGGL(gconv_fused, grid, block, 0, stream,
                       x, dist, W, bias, idx, out);
}

// Round 2
// 242.101 us; speedup vs baseline: 1.3185x; 1.3185x over previous
//
#include <hip/hip_runtime.h>

typedef __attribute__((ext_vector_type(8))) short short8;
typedef __attribute__((ext_vector_type(4))) float f32x4;

constexpr int B_ = 4, T_ = 12, N_ = 2000, K_ = 10, F_ = 64, H_ = 8;
constexpr int AST = 72;   // A-tile LDS row stride in bf16 elems (64 + 8 pad -> conflict-free b128 reads)

// fp32 -> bf16 (RNE) and back, via bit ops (no type-system surprises)
static __device__ __forceinline__ short f2bf(float f) {
    unsigned u = __float_as_uint(f);
    unsigned r = (u + 0x7FFFu + ((u >> 16) & 1u)) >> 16;
    return (short)(r & 0xFFFFu);
}
static __device__ __forceinline__ float bf2f(short s) {
    return __uint_as_float(((unsigned)(unsigned short)s) << 16);
}

__global__ __launch_bounds__(256, 4)
void gconv_mfma(const float* __restrict__ x,
                const float* __restrict__ dist,
                const float* __restrict__ W,
                const float* __restrict__ bias,
                const int*   __restrict__ idx,
                float* __restrict__ out)
{
    // A = blended agg, M=96 rows (m = t*8+h), K=64 cols (f), split into bf16 hi+lo
    __shared__ short Ahi[96 * AST];          // 13.8 KB
    __shared__ short Alo[96 * AST];          // 13.8 KB
    __shared__ float bnd[4][H_][F_];         // 8 KB: each wave's last raw agg row (t = 3w+2)

    const int tid  = threadIdx.x;
    const int wave = tid >> 6;
    const int lane = tid & 63;
    const int n = blockIdx.x % N_;
    const int b = blockIdx.x / N_;
    const int t0 = wave * 3;                 // this wave owns t in [t0, t0+3)

    // ---- per-neighbor base weight r_k = exp(-d^2/(36*8)); w[k][h] = r_k^(h+1) ----
    float rk[K_];
    int   nb[K_];
    #pragma unroll
    for (int k = 0; k < K_; ++k) {
        nb[k] = idx[n * K_ + k] * F_;                 // block-uniform -> scalar regs
        float d = dist[n * K_ + k];
        rk[k] = __expf(d * d * (-1.0f / 288.0f));
    }

    // ---- Phase 1: gather-FMA, wave owns 3 t's x all 8 heads, f = lane ----
    float acc[3][H_];
    #pragma unroll
    for (int i = 0; i < 3; ++i)
        #pragma unroll
        for (int h = 0; h < H_; ++h) acc[i][h] = 0.f;

    const float* xb = x + ((size_t)b * T_ + t0) * (size_t)(N_ * F_) + lane;
    #pragma unroll
    for (int k = 0; k < K_; ++k) {
        float x0 = xb[nb[k]];                          // coalesced 256B row
        float x1 = xb[nb[k] + N_ * F_];
        float x2 = xb[nb[k] + 2 * N_ * F_];
        float wgt = rk[k];
        #pragma unroll
        for (int h = 0; h < H_; ++h) {
            acc[0][h] = fmaf(x0, wgt, acc[0][h]);
            acc[1][h] = fmaf(x1, wgt, acc[1][h]);
            acc[2][h] = fmaf(x2, wgt, acc[2][h]);
            wgt *= rk[k];                              // next head's lambda
        }
    }

    // ---- exchange raw boundary row (t = 3w+2) for the next wave's blend ----
    #pragma unroll
    for (int h = 0; h < H_; ++h) bnd[wave][h][lane] = acc[2][h];
    __syncthreads();

    // ---- temporal blend in registers, descending t (t=0 stays raw) ----
    #pragma unroll
    for (int h = 0; h < H_; ++h) {
        acc[2][h] = fmaf(0.8f, acc[2][h], 0.2f * acc[1][h]);
        acc[1][h] = fmaf(0.8f, acc[1][h], 0.2f * acc[0][h]);
    }
    if (wave > 0) {
        #pragma unroll
        for (int h = 0; h < H_; ++h)
            acc[0][h] = fmaf(0.8f, acc[0][h], 0.2f * bnd[wave - 1][h][lane]);
    }

    // ---- write A (hi/lo bf16 split) to LDS in MFMA-friendly layout ----
    #pragma unroll
    for (int i = 0; i < 3; ++i)
        #pragma unroll
        for (int h = 0; h < H_; ++h) {
            int m = (t0 + i) * H_ + h;
            float v  = acc[i][h];
            short hi = f2bf(v);
            Ahi[m * AST + lane] = hi;
            Alo[m * AST + lane] = f2bf(v - bf2f(hi));
        }
    __syncthreads();

    // ---- Phase 2: MFMA GEMM. wave w owns output cols fo in [16w, 16w+16) ----
    // B[k][col] = W[col][k]: lane reads W row `colw`, contiguous k -> direct from global
    const int colw = (wave << 4) + (lane & 15);
    const int kg   = lane >> 4;                        // k-group 0..3 (8 elems each)
    short8 bh[2], bl[2];
    #pragma unroll
    for (int kb = 0; kb < 2; ++kb) {
        const float* wp = W + colw * F_ + kb * 32 + kg * 8;
        #pragma unroll
        for (int j = 0; j < 8; ++j) {
            float wv = wp[j];
            short hi = f2bf(wv);
            bh[kb][j] = hi;
            bl[kb][j] = f2bf(wv - bf2f(hi));
        }
    }
    const float bs = bias[colw];

    #pragma unroll
    for (int mt = 0; mt < 6; ++mt) {
        const short* ap = &Ahi[(mt * 16 + (lane & 15)) * AST + kg * 8];
        const short* lp = &Alo[(mt * 16 + (lane & 15)) * AST + kg * 8];
        short8 a0 = *(const short8*)ap;               // ds_read_b128, 2-way banks (free)
        short8 a1 = *(const short8*)(ap + 32);        // k + 32
        short8 l0 = *(const short8*)lp;
        short8 l1 = *(const short8*)(lp + 32);

        f32x4 c = {0.f, 0.f, 0.f, 0.f};
        // split product: A*W = Ahi*Wlo + Alo*Whi + Ahi*Whi  (Alo*Wlo negligible)
        c = __builtin_amdgcn_mfma_f32_16x16x32_bf16(a0, bl[0], c, 0, 0, 0);
        c = __builtin_amdgcn_mfma_f32_16x16x32_bf16(a1, bl[1], c, 0, 0, 0);
        c = __builtin_amdgcn_mfma_f32_16x16x32_bf16(l0, bh[0], c, 0, 0, 0);
        c = __builtin_amdgcn_mfma_f32_16x16x32_bf16(l1, bh[1], c, 0, 0, 0);
        c = __builtin_amdgcn_mfma_f32_16x16x32_bf16(a0, bh[0], c, 0, 0, 0);
        c = __builtin_amdgcn_mfma_f32_16x16x32_bf16(a1, bh[1], c, 0, 0, 0);

        // D layout (m89-verified): col = lane&15, row = (lane>>4)*4 + reg
        #pragma unroll
        for (int r = 0; r < 4; ++r) {
            int m = mt * 16 + (lane >> 4) * 4 + r;
            int t = m >> 3, h = m & 7;
            float v = fmaxf(c[r] + bs, 0.f);
            out[(((size_t)(b * T_ + t) * N_ + n) * H_ + h) * F_ + colw] = v;
        }
    }
}

extern "C" void kernel_launch(void* const* d_in, const int* in_sizes, int n_in,
                              void* d_out, int out_size, void* d_ws, size_t ws_size,
                              hipStream_t stream) {
    const float* x    = (const float*)d_in[0];
    const float* dist = (const float*)d_in[1];
    const float* W    = (const float*)d_in[2];
    const float* bias = (const float*)d_in[3];
    const int*   idx  = (const int*)d_in[4];
    float* out = (float*)d_out;

    hipLaunchKernelGGL(gconv_mfma, dim3(B_ * N_), dim3(256), 0, stream,
                       x, dist, W, bias, idx, out);
}